// Round 4
// baseline (293.035 us; speedup 1.0000x reference)
//
#include <hip/hip_runtime.h>
#include <hip/hip_bf16.h>

constexpr int NR = 12288;   // nodes
constexpr int KF = 256;     // in features
constexpr int DF = 128;     // out features
#define NEGBIG (-1e30f)

typedef __attribute__((ext_vector_type(8))) __bf16 bf16x8;
typedef __attribute__((ext_vector_type(4))) float  f32x4;

__device__ __forceinline__ unsigned short f2bf(float f) {
    union { float f; unsigned u; } v; v.f = f;
    unsigned r = v.u + 0x7FFFu + ((v.u >> 16) & 1u);
    return (unsigned short)(r >> 16);
}

// Raw barrier WITHOUT the implicit vmcnt(0) drain __syncthreads carries.
// LDS ops must be complete (lgkmcnt 0) for producer/consumer visibility;
// global loads stay in flight across it (the whole point).
#define BARRIER() do { \
    asm volatile("s_waitcnt lgkmcnt(0)" ::: "memory"); \
    __builtin_amdgcn_s_barrier(); \
    asm volatile("" ::: "memory"); \
} while (0)

// ---------- Kernel A: h = x@W (fp32 regs), emit hbT (bf16, transposed) + s1/s2
__global__ __launch_bounds__(256) void k_gemm_h(
    const float* __restrict__ x, const float* __restrict__ W,
    const float* __restrict__ a1, const float* __restrict__ a2,
    unsigned short* __restrict__ hbT, float* __restrict__ s1, float* __restrict__ s2)
{
    __shared__ __align__(16) float xs[64][65];
    __shared__ __align__(16) float ws[64][132];
    const int t  = threadIdx.x;
    const int tx = t & 15, ty = t >> 4;
    const int rowbase = blockIdx.x * 64;

    float acc[4][8];
#pragma unroll
    for (int i = 0; i < 4; ++i)
#pragma unroll
        for (int j = 0; j < 8; ++j) acc[i][j] = 0.f;

    for (int kt = 0; kt < KF; kt += 64) {
        {   // stage x tile [64][64]
            int row = t >> 2, k0 = (t & 3) * 16;
            const float4* src = (const float4*)(x + (size_t)(rowbase + row) * KF + kt + k0);
            float4 v0 = src[0], v1 = src[1], v2 = src[2], v3 = src[3];
            xs[row][k0+ 0]=v0.x; xs[row][k0+ 1]=v0.y; xs[row][k0+ 2]=v0.z; xs[row][k0+ 3]=v0.w;
            xs[row][k0+ 4]=v1.x; xs[row][k0+ 5]=v1.y; xs[row][k0+ 6]=v1.z; xs[row][k0+ 7]=v1.w;
            xs[row][k0+ 8]=v2.x; xs[row][k0+ 9]=v2.y; xs[row][k0+10]=v2.z; xs[row][k0+11]=v2.w;
            xs[row][k0+12]=v3.x; xs[row][k0+13]=v3.y; xs[row][k0+14]=v3.z; xs[row][k0+15]=v3.w;
        }
        {   // stage W tile [64][128]
            int k = t >> 2, c0 = (t & 3) * 32;
            const float4* src = (const float4*)(W + (size_t)(kt + k) * DF + c0);
#pragma unroll
            for (int j = 0; j < 8; ++j)
                *(float4*)&ws[k][c0 + j * 4] = src[j];
        }
        __syncthreads();
#pragma unroll 4
        for (int k = 0; k < 64; ++k) {
            float xv[4];
#pragma unroll
            for (int ri = 0; ri < 4; ++ri) xv[ri] = xs[ty * 4 + ri][k];
            float4 w0 = *(float4*)&ws[k][tx * 8];
            float4 w1 = *(float4*)&ws[k][tx * 8 + 4];
#pragma unroll
            for (int ri = 0; ri < 4; ++ri) {
                acc[ri][0] += xv[ri] * w0.x; acc[ri][1] += xv[ri] * w0.y;
                acc[ri][2] += xv[ri] * w0.z; acc[ri][3] += xv[ri] * w0.w;
                acc[ri][4] += xv[ri] * w1.x; acc[ri][5] += xv[ri] * w1.y;
                acc[ri][6] += xv[ri] * w1.z; acc[ri][7] += xv[ri] * w1.w;
            }
        }
        __syncthreads();
    }
    // hbT (transposed bf16) for the PV MFMA
#pragma unroll
    for (int ci = 0; ci < 8; ++ci) {
        int col = tx * 8 + ci;
        ushort4 u;
        u.x = f2bf(acc[0][ci]); u.y = f2bf(acc[1][ci]);
        u.z = f2bf(acc[2][ci]); u.w = f2bf(acc[3][ci]);
        *(ushort4*)(hbT + (size_t)col * NR + rowbase + ty * 4) = u;
    }
    // s1 = h@a1, s2 = h@a2 fused
    float4 a1lo = *(const float4*)(a1 + tx * 8), a1hi = *(const float4*)(a1 + tx * 8 + 4);
    float4 a2lo = *(const float4*)(a2 + tx * 8), a2hi = *(const float4*)(a2 + tx * 8 + 4);
#pragma unroll
    for (int ri = 0; ri < 4; ++ri) {
        float p1 = acc[ri][0]*a1lo.x + acc[ri][1]*a1lo.y + acc[ri][2]*a1lo.z + acc[ri][3]*a1lo.w
                 + acc[ri][4]*a1hi.x + acc[ri][5]*a1hi.y + acc[ri][6]*a1hi.z + acc[ri][7]*a1hi.w;
        float p2 = acc[ri][0]*a2lo.x + acc[ri][1]*a2lo.y + acc[ri][2]*a2lo.z + acc[ri][3]*a2lo.w
                 + acc[ri][4]*a2hi.x + acc[ri][5]*a2hi.y + acc[ri][6]*a2hi.z + acc[ri][7]*a2hi.w;
#pragma unroll
        for (int off = 8; off > 0; off >>= 1) {
            p1 += __shfl_xor(p1, off);
            p2 += __shfl_xor(p2, off);
        }
        if (tx == 0) {
            s1[rowbase + ty * 4 + ri] = p1;
            s2[rowbase + ty * 4 + ri] = p2;
        }
    }
}

// ---------- Kernel A2: global max of s1 (one block) --------------------------
__global__ __launch_bounds__(1024) void k_gmax(
    const float* __restrict__ s1, float* __restrict__ gmax)
{
    __shared__ float red[16];
    const int t = threadIdx.x;
    float m = NEGBIG;
    const float4* s4 = (const float4*)s1;
    for (int i = t; i < NR / 4; i += 1024) {
        float4 v = s4[i];
        m = fmaxf(fmaxf(v.x, v.y), fmaxf(fmaxf(v.z, v.w), m));
    }
#pragma unroll
    for (int off = 32; off > 0; off >>= 1) m = fmaxf(m, __shfl_xor(m, off));
    if ((t & 63) == 0) red[t >> 6] = m;
    __syncthreads();
    if (t < 16) {
        m = red[t];
#pragma unroll
        for (int off = 8; off > 0; off >>= 1) m = fmaxf(m, __shfl_xor(m, off));
        if (t == 0) gmax[0] = m;
    }
}

// ---------- Kernel B: flash over adj. LDS dbuf, raw barriers (no vmcnt drain),
// depth-1 register prefetch. grid (192, CH) x 256 thr (4 waves x 16 rows). K=32.
__global__ __launch_bounds__(256, 4) void k_flash(
    const int* __restrict__ adj, const unsigned short* __restrict__ hbT,
    const float* __restrict__ s1, const float* __restrict__ s2,
    const float* __restrict__ gmaxp,
    float* __restrict__ num, float* __restrict__ lC, int CW)
{
    __shared__ __align__(16) unsigned short hbuf[2][128][40]; // padded: 0 conflicts (measured R1)
    const int t    = threadIdx.x;
    const int wid  = t >> 6, lane = t & 63;
    const int r    = lane & 15, g = lane >> 4;
    const int rowb = blockIdx.x * 64;
    const int prow = rowb + wid * 16 + r;
    const int chunk = blockIdx.y;
    const int j0 = chunk * CW;

    const float gm  = gmaxp[0];
    const float s2r = s2[prow];
    const float zub = s2r + gm;
    const float Mi  = fmaxf(zub, 0.2f * zub);   // lrelu(upper bound) >= every row logit

    float lsum = 0.f;
    f32x4 acc[8];
#pragma unroll
    for (int f = 0; f < 8; ++f) acc[f] = f32x4{0.f, 0.f, 0.f, 0.f};

    const int*   ap = adj + (size_t)prow * NR + j0 + g * 8;
    const float* sp = s1 + j0 + g * 8;
    const int sr = t >> 1, scol = (t & 1) * 16;
    const unsigned short* hs = hbT + (size_t)sr * NR + j0 + scol;

    const int nsteps = CW >> 5;

    // prologue: stage tile 0, load adj/s1 slice 0
    bf16x8 Ta = *(const bf16x8*)(hs);
    bf16x8 Tb = *(const bf16x8*)(hs + 8);
    int4   Aa = *(const int4*)(ap);
    int4   Ab = *(const int4*)(ap + 4);
    float4 Sa = *(const float4*)(sp);
    float4 Sb = *(const float4*)(sp + 4);
    *(bf16x8*)&hbuf[0][sr][scol]     = Ta;
    *(bf16x8*)&hbuf[0][sr][scol + 8] = Tb;
    BARRIER();

    int cur = 0;
#define PROC(mm, ss, idx) { \
        float t0 = (ss) + s2r; \
        float lr = fmaxf(t0, 0.2f * t0); \
        float e  = ((mm) > 0) ? lr : NEGBIG; \
        float p  = __expf(e - Mi); \
        lsum += p; \
        pf[idx] = (__bf16)p; }

    for (int it = 0; it < nsteps - 1; ++it) {
        // prefetch it+1. ISSUE ORDER MATTERS: hbT first (ds_write below waits
        // only for these, vmcnt(4) leaves adj/s1 in flight across the barrier).
        hs += 32; ap += 32; sp += 32;
        bf16x8 NTa = *(const bf16x8*)(hs);
        bf16x8 NTb = *(const bf16x8*)(hs + 8);
        int4   NAa = *(const int4*)(ap);
        int4   NAb = *(const int4*)(ap + 4);
        float4 NSa = *(const float4*)(sp);
        float4 NSb = *(const float4*)(sp + 4);

        bf16x8 pf;
        PROC(Aa.x, Sa.x, 0) PROC(Aa.y, Sa.y, 1)
        PROC(Aa.z, Sa.z, 2) PROC(Aa.w, Sa.w, 3)
        PROC(Ab.x, Sb.x, 4) PROC(Ab.y, Sb.y, 5)
        PROC(Ab.z, Sb.z, 6) PROC(Ab.w, Sb.w, 7)

#pragma unroll
        for (int f = 0; f < 8; ++f) {
            bf16x8 bfr = *(const bf16x8*)&hbuf[cur][f * 16 + r][g * 8];
            acc[f] = __builtin_amdgcn_mfma_f32_16x16x32_bf16(pf, bfr, acc[f], 0, 0, 0);
        }

        *(bf16x8*)&hbuf[cur ^ 1][sr][scol]     = NTa;
        *(bf16x8*)&hbuf[cur ^ 1][sr][scol + 8] = NTb;
        BARRIER();
        Aa = NAa; Ab = NAb; Sa = NSa; Sb = NSb;
        cur ^= 1;
    }
    {   // final iteration: no prefetch, no barrier needed after
        bf16x8 pf;
        PROC(Aa.x, Sa.x, 0) PROC(Aa.y, Sa.y, 1)
        PROC(Aa.z, Sa.z, 2) PROC(Aa.w, Sa.w, 3)
        PROC(Ab.x, Sb.x, 4) PROC(Ab.y, Sb.y, 5)
        PROC(Ab.z, Sb.z, 6) PROC(Ab.w, Sb.w, 7)
#pragma unroll
        for (int f = 0; f < 8; ++f) {
            bf16x8 bfr = *(const bf16x8*)&hbuf[cur][f * 16 + r][g * 8];
            acc[f] = __builtin_amdgcn_mfma_f32_16x16x32_bf16(pf, bfr, acc[f], 0, 0, 0);
        }
    }
#undef PROC

    lsum += __shfl_xor(lsum, 16);
    lsum += __shfl_xor(lsum, 32);
    if (g == 0) lC[(size_t)chunk * NR + prow] = lsum;

    float* nb = num + (size_t)chunk * NR * DF;
#pragma unroll
    for (int f = 0; f < 8; ++f)
#pragma unroll
        for (int q = 0; q < 4; ++q) {
            int row = rowb + wid * 16 + g * 4 + q;   // C/D layout: row=(lane>>4)*4+reg
            nb[(size_t)row * DF + f * 16 + r] = acc[f][q];
        }
}

// ---------- Kernel C: combine chunk partials (shared M_i -> plain sums) ------
__global__ __launch_bounds__(256) void k_comb(
    const float* __restrict__ num, const float* __restrict__ lC,
    float* __restrict__ out, int CH)
{
    const int t   = threadIdx.x;
    const int row = blockIdx.x * 2 + (t >> 7);
    const int f   = t & 127;
    float L = 0.f, o = 0.f;
    for (int c = 0; c < CH; ++c) {
        L += lC[(size_t)c * NR + row];
        o += num[(size_t)c * NR * DF + (size_t)row * DF + f];
    }
    out[(size_t)row * DF + f] = o / L;
}

extern "C" void kernel_launch(void* const* d_in, const int* in_sizes, int n_in,
                              void* d_out, int out_size, void* d_ws, size_t ws_size,
                              hipStream_t stream)
{
    const float* x   = (const float*)d_in[0];
    const int*   adj = (const int*)d_in[1];
    const float* W   = (const float*)d_in[2];
    const float* a1  = (const float*)d_in[3];
    const float* a2  = (const float*)d_in[4];
    float* out = (float*)d_out;

    char* p = (char*)d_ws;
    unsigned short* hbT = (unsigned short*)p; p += (size_t)DF * NR * 2;
    float*          s1  = (float*)p;          p += (size_t)NR * 4;
    float*          s2  = (float*)p;          p += (size_t)NR * 4;
    float*          gmx = (float*)p;          p += 256;
    size_t base = (size_t)(p - (char*)d_ws);
    size_t per  = (size_t)NR * DF * 4 + (size_t)NR * 4;
    int CH = 8;
    while (CH > 1 && base + (size_t)CH * per > ws_size) CH >>= 1;
    float* numb = (float*)p; p += (size_t)CH * NR * DF * 4;
    float* lC   = (float*)p;

    k_gemm_h<<<NR / 64, 256, 0, stream>>>(x, W, a1, a2, hbT, s1, s2);
    k_gmax<<<1, 1024, 0, stream>>>(s1, gmx);
    k_flash<<<dim3(NR / 64, CH), 256, 0, stream>>>(adj, hbT, s1, s2, gmx, numb, lC, NR / CH);
    k_comb<<<NR / 2, 256, 0, stream>>>(numb, lC, out, CH);
}

// Round 5
// 255.351 us; speedup vs baseline: 1.1476x; 1.1476x over previous
//
#include <hip/hip_runtime.h>
#include <hip/hip_bf16.h>

constexpr int NR = 12288;   // nodes
constexpr int KF = 256;     // in features
constexpr int DF = 128;     // out features
constexpr int CH = 12;      // column chunks
constexpr int CW = NR / CH; // 1024 cols per chunk
constexpr int NSTEP = CW / 32;
#define NEGBIG (-1e30f)

typedef __attribute__((ext_vector_type(8))) __bf16 bf16x8;
typedef __attribute__((ext_vector_type(4))) float  f32x4;

__device__ __forceinline__ unsigned short f2bf(float f) {
    union { float f; unsigned u; } v; v.f = f;
    unsigned r = v.u + 0x7FFFu + ((v.u >> 16) & 1u);
    return (unsigned short)(r >> 16);
}

__device__ __forceinline__ void gload16(const void* g, void* l) {
    __builtin_amdgcn_global_load_lds(
        (const __attribute__((address_space(1))) void*)g,
        (__attribute__((address_space(3))) void*)l, 16, 0, 0);
}

// ---------- Kernel A: h = x@W (fp32 regs), emit hbT (bf16, transposed) + s1/s2
__global__ __launch_bounds__(256) void k_gemm_h(
    const float* __restrict__ x, const float* __restrict__ W,
    const float* __restrict__ a1, const float* __restrict__ a2,
    unsigned short* __restrict__ hbT, float* __restrict__ s1, float* __restrict__ s2)
{
    __shared__ __align__(16) float xs[64][65];
    __shared__ __align__(16) float ws[64][132];
    const int t  = threadIdx.x;
    const int tx = t & 15, ty = t >> 4;
    const int rowbase = blockIdx.x * 64;

    float acc[4][8];
#pragma unroll
    for (int i = 0; i < 4; ++i)
#pragma unroll
        for (int j = 0; j < 8; ++j) acc[i][j] = 0.f;

    for (int kt = 0; kt < KF; kt += 64) {
        {   // stage x tile [64][64]
            int row = t >> 2, k0 = (t & 3) * 16;
            const float4* src = (const float4*)(x + (size_t)(rowbase + row) * KF + kt + k0);
            float4 v0 = src[0], v1 = src[1], v2 = src[2], v3 = src[3];
            xs[row][k0+ 0]=v0.x; xs[row][k0+ 1]=v0.y; xs[row][k0+ 2]=v0.z; xs[row][k0+ 3]=v0.w;
            xs[row][k0+ 4]=v1.x; xs[row][k0+ 5]=v1.y; xs[row][k0+ 6]=v1.z; xs[row][k0+ 7]=v1.w;
            xs[row][k0+ 8]=v2.x; xs[row][k0+ 9]=v2.y; xs[row][k0+10]=v2.z; xs[row][k0+11]=v2.w;
            xs[row][k0+12]=v3.x; xs[row][k0+13]=v3.y; xs[row][k0+14]=v3.z; xs[row][k0+15]=v3.w;
        }
        {   // stage W tile [64][128]
            int k = t >> 2, c0 = (t & 3) * 32;
            const float4* src = (const float4*)(W + (size_t)(kt + k) * DF + c0);
#pragma unroll
            for (int j = 0; j < 8; ++j)
                *(float4*)&ws[k][c0 + j * 4] = src[j];
        }
        __syncthreads();
#pragma unroll 4
        for (int k = 0; k < 64; ++k) {
            float xv[4];
#pragma unroll
            for (int ri = 0; ri < 4; ++ri) xv[ri] = xs[ty * 4 + ri][k];
            float4 w0 = *(float4*)&ws[k][tx * 8];
            float4 w1 = *(float4*)&ws[k][tx * 8 + 4];
#pragma unroll
            for (int ri = 0; ri < 4; ++ri) {
                acc[ri][0] += xv[ri] * w0.x; acc[ri][1] += xv[ri] * w0.y;
                acc[ri][2] += xv[ri] * w0.z; acc[ri][3] += xv[ri] * w0.w;
                acc[ri][4] += xv[ri] * w1.x; acc[ri][5] += xv[ri] * w1.y;
                acc[ri][6] += xv[ri] * w1.z; acc[ri][7] += xv[ri] * w1.w;
            }
        }
        __syncthreads();
    }
#pragma unroll
    for (int ci = 0; ci < 8; ++ci) {
        int col = tx * 8 + ci;
        ushort4 u;
        u.x = f2bf(acc[0][ci]); u.y = f2bf(acc[1][ci]);
        u.z = f2bf(acc[2][ci]); u.w = f2bf(acc[3][ci]);
        *(ushort4*)(hbT + (size_t)col * NR + rowbase + ty * 4) = u;
    }
    float4 a1lo = *(const float4*)(a1 + tx * 8), a1hi = *(const float4*)(a1 + tx * 8 + 4);
    float4 a2lo = *(const float4*)(a2 + tx * 8), a2hi = *(const float4*)(a2 + tx * 8 + 4);
#pragma unroll
    for (int ri = 0; ri < 4; ++ri) {
        float p1 = acc[ri][0]*a1lo.x + acc[ri][1]*a1lo.y + acc[ri][2]*a1lo.z + acc[ri][3]*a1lo.w
                 + acc[ri][4]*a1hi.x + acc[ri][5]*a1hi.y + acc[ri][6]*a1hi.z + acc[ri][7]*a1hi.w;
        float p2 = acc[ri][0]*a2lo.x + acc[ri][1]*a2lo.y + acc[ri][2]*a2lo.z + acc[ri][3]*a2lo.w
                 + acc[ri][4]*a2hi.x + acc[ri][5]*a2hi.y + acc[ri][6]*a2hi.z + acc[ri][7]*a2hi.w;
#pragma unroll
        for (int off = 8; off > 0; off >>= 1) {
            p1 += __shfl_xor(p1, off);
            p2 += __shfl_xor(p2, off);
        }
        if (tx == 0) {
            s1[rowbase + ty * 4 + ri] = p1;
            s2[rowbase + ty * 4 + ri] = p2;
        }
    }
}

// ---------- Kernel A2: global max of s1 (one block) --------------------------
__global__ __launch_bounds__(1024) void k_gmax(
    const float* __restrict__ s1, float* __restrict__ gmax)
{
    __shared__ float red[16];
    const int t = threadIdx.x;
    float m = NEGBIG;
    const float4* s4 = (const float4*)s1;
    for (int i = t; i < NR / 4; i += 1024) {
        float4 v = s4[i];
        m = fmaxf(fmaxf(v.x, v.y), fmaxf(fmaxf(v.z, v.w), m));
    }
#pragma unroll
    for (int off = 32; off > 0; off >>= 1) m = fmaxf(m, __shfl_xor(m, off));
    if ((t & 63) == 0) red[t >> 6] = m;
    __syncthreads();
    if (t < 16) {
        m = red[t];
#pragma unroll
        for (int off = 8; off > 0; off >>= 1) m = fmaxf(m, __shfl_xor(m, off));
        if (t == 0) gmax[0] = m;
    }
}

// ---------- Kernel B: flash over adj. global_load_lds 3-slot ring, counted vmcnt.
// grid (192, CH) x 256 thr (4 waves x 16 rows). K-step 32.
__global__ __launch_bounds__(256, 3) void k_flash(
    const int* __restrict__ adj, const unsigned short* __restrict__ hbT,
    const float* __restrict__ s1, const float* __restrict__ s2,
    const float* __restrict__ gmaxp,
    float* __restrict__ num, float* __restrict__ lC)
{
    // ring stages: adj [64 rows][8 slots of 16B, slot^ (row&7)],
    //              hbT [128 feats][4 slots of 16B, slot ^ ((row>>1)&3)]
    __shared__ __align__(16) int            adjring[3][2048];
    __shared__ __align__(16) unsigned short hbtring[3][4096];
    __shared__ __align__(16) float          s1lds[CW];

    const int t    = threadIdx.x;
    const int wid  = t >> 6, lane = t & 63;
    const int r    = lane & 15, g = lane >> 4;
    const int rowb = blockIdx.x * 64;
    const int prow = rowb + wid * 16 + r;
    const int chunk = blockIdx.y;
    const int j0 = chunk * CW;

    // one-time: stage s1 chunk (CW floats) into LDS
    *(float4*)&s1lds[t * 4] = *(const float4*)(s1 + j0 + t * 4);

    const float gm  = gmaxp[0];
    const float s2r = s2[prow];
    const float zub = s2r + gm;
    const float Mi  = fmaxf(zub, 0.2f * zub);   // lrelu(upper bound) >= every row logit

    // ---- staging sources (per-lane, pre-swizzled so LDS[row][slot] = col slot^f(row))
    const int arow  = wid * 16 + (lane >> 3);                   // adj inst k adds 8 rows
    const int acol4 = ((lane & 7) ^ (lane >> 3)) * 4;
    const int* agp0 = adj + (size_t)(rowb + arow) * NR + j0 + acol4;
    const int* agp1 = agp0 + (size_t)8 * NR;
    const int aldso0 = (wid * 16 + 0) * 128;                    // LDS byte offs (wave-uniform)
    const int aldso1 = (wid * 16 + 8) * 128;

    const int hrow  = wid * 32 + (lane >> 2);                   // hbT inst k adds 16 feats
    const int hcol8 = ((lane & 3) ^ ((lane >> 3) & 3)) * 8;
    const unsigned short* hgp0 = hbT + (size_t)hrow * NR + j0 + hcol8;
    const unsigned short* hgp1 = hgp0 + (size_t)16 * NR;
    const int hldso0 = (wid * 32 + 0) * 64;
    const int hldso1 = (wid * 32 + 16) * 64;

    // ---- read-side swizzled offsets (lane-constant)
    const int a_off0 = (wid * 16 + r) * 128 + (((2 * g + 0) ^ (r & 7)) * 16);
    const int a_off1 = (wid * 16 + r) * 128 + (((2 * g + 1) ^ (r & 7)) * 16);
    const int h_base = r * 64 + ((g ^ ((r >> 1) & 3)) * 16);    // + f*1024

#define ISSUE(st) do { \
        const int sl_ = (st) % 3; \
        const size_t go_ = (size_t)(((st) % NSTEP) * 32); \
        gload16(agp0 + go_, (char*)&adjring[sl_][0] + aldso0); \
        gload16(agp1 + go_, (char*)&adjring[sl_][0] + aldso1); \
        gload16(hgp0 + go_, (char*)&hbtring[sl_][0] + hldso0); \
        gload16(hgp1 + go_, (char*)&hbtring[sl_][0] + hldso1); \
    } while (0)

    float lsum = 0.f;
    f32x4 acc[8];
#pragma unroll
    for (int f = 0; f < 8; ++f) acc[f] = f32x4{0.f, 0.f, 0.f, 0.f};

    ISSUE(0);
    ISSUE(1);

    for (int j = 0; j < NSTEP; ++j) {
        // stage j landed when <=4 of our vmem remain (stage j+1 only).
        asm volatile("s_waitcnt vmcnt(4) lgkmcnt(0)" ::: "memory");
        __builtin_amdgcn_s_barrier();
        __builtin_amdgcn_sched_barrier(0);
        ISSUE(j + 2);   // safe: slot (j+2)%3 == (j-1)%3 fully consumed before barrier

        const int sl = j % 3;
        const int4 Aa = *(const int4*)((const char*)&adjring[sl][0] + a_off0);
        const int4 Ab = *(const int4*)((const char*)&adjring[sl][0] + a_off1);
        const float4 Sa = *(const float4*)&s1lds[j * 32 + g * 8];
        const float4 Sb = *(const float4*)&s1lds[j * 32 + g * 8 + 4];

        bf16x8 pf;
#define PROC(mm, ss, idx) { \
            float t0 = (ss) + s2r; \
            float lr = fmaxf(t0, 0.2f * t0); \
            float q  = __expf(lr - Mi); \
            float p  = ((mm) > 0) ? q : 0.f; \
            lsum += p; \
            pf[idx] = (__bf16)p; }
        PROC(Aa.x, Sa.x, 0) PROC(Aa.y, Sa.y, 1)
        PROC(Aa.z, Sa.z, 2) PROC(Aa.w, Sa.w, 3)
        PROC(Ab.x, Sb.x, 4) PROC(Ab.y, Sb.y, 5)
        PROC(Ab.z, Sb.z, 6) PROC(Ab.w, Sb.w, 7)
#undef PROC

        const char* hb = (const char*)&hbtring[sl][0] + h_base;
#pragma unroll
        for (int f = 0; f < 8; ++f) {
            bf16x8 bfr = *(const bf16x8*)(hb + f * 1024);
            acc[f] = __builtin_amdgcn_mfma_f32_16x16x32_bf16(pf, bfr, acc[f], 0, 0, 0);
        }
    }
#undef ISSUE

    lsum += __shfl_xor(lsum, 16);
    lsum += __shfl_xor(lsum, 32);
    if (g == 0) lC[(size_t)chunk * NR + prow] = lsum;

    float* nb = num + (size_t)chunk * NR * DF;
#pragma unroll
    for (int f = 0; f < 8; ++f)
#pragma unroll
        for (int q = 0; q < 4; ++q) {
            int row = rowb + wid * 16 + g * 4 + q;   // C/D layout: row=(lane>>4)*4+reg
            nb[(size_t)row * DF + f * 16 + r] = acc[f][q];
        }
}

// ---------- Kernel C: combine chunk partials (shared M_i -> plain sums) ------
__global__ __launch_bounds__(256) void k_comb(
    const float* __restrict__ num, const float* __restrict__ lC,
    float* __restrict__ out)
{
    const int t   = threadIdx.x;
    const int row = blockIdx.x * 2 + (t >> 7);
    const int f   = t & 127;
    float L = 0.f, o = 0.f;
    for (int c = 0; c < CH; ++c) {
        L += lC[(size_t)c * NR + row];
        o += num[(size_t)c * NR * DF + (size_t)row * DF + f];
    }
    out[(size_t)row * DF + f] = o / L;
}

extern "C" void kernel_launch(void* const* d_in, const int* in_sizes, int n_in,
                              void* d_out, int out_size, void* d_ws, size_t ws_size,
                              hipStream_t stream)
{
    const float* x   = (const float*)d_in[0];
    const int*   adj = (const int*)d_in[1];
    const float* W   = (const float*)d_in[2];
    const float* a1  = (const float*)d_in[3];
    const float* a2  = (const float*)d_in[4];
    float* out = (float*)d_out;

    char* p = (char*)d_ws;
    unsigned short* hbT = (unsigned short*)p; p += (size_t)DF * NR * 2;
    float*          s1  = (float*)p;          p += (size_t)NR * 4;
    float*          s2  = (float*)p;          p += (size_t)NR * 4;
    float*          gmx = (float*)p;          p += 256;
    float*          numb = (float*)p;         p += (size_t)CH * NR * DF * 4;
    float*          lC   = (float*)p;

    k_gemm_h<<<NR / 64, 256, 0, stream>>>(x, W, a1, a2, hbT, s1, s2);
    k_gmax<<<1, 1024, 0, stream>>>(s1, gmx);
    k_flash<<<dim3(NR / 64, CH), 256, 0, stream>>>(adj, hbT, s1, s2, gmx, numb, lC);
    k_comb<<<NR / 2, 256, 0, stream>>>(numb, lC, out);
}

// Round 6
// 227.555 us; speedup vs baseline: 1.2878x; 1.1222x over previous
//
#include <hip/hip_runtime.h>
#include <hip/hip_bf16.h>

constexpr int NR = 12288;   // nodes
constexpr int KF = 256;     // in features
constexpr int DF = 128;     // out features
constexpr int CH = 16;      // column chunks (1536 blocks = 3 exact rounds of 512 slots)
constexpr int CW = NR / CH; // 768 cols per chunk
constexpr int NSTEP = CW / 32;
constexpr int ROWS = 128;   // Q-rows per block (8 waves x 16 rows)
#define NEGBIG (-1e30f)

typedef __attribute__((ext_vector_type(8))) __bf16 bf16x8;
typedef __attribute__((ext_vector_type(4))) float  f32x4;

__device__ __forceinline__ unsigned short f2bf(float f) {
    union { float f; unsigned u; } v; v.f = f;
    unsigned r = v.u + 0x7FFFu + ((v.u >> 16) & 1u);
    return (unsigned short)(r >> 16);
}

__device__ __forceinline__ void gload16(const void* g, void* l) {
    __builtin_amdgcn_global_load_lds(
        (const __attribute__((address_space(1))) void*)g,
        (__attribute__((address_space(3))) void*)l, 16, 0, 0);
}

// ---------- Kernel A: h = x@W (fp32 regs), emit hbT (bf16, transposed) + s1/s2
__global__ __launch_bounds__(256) void k_gemm_h(
    const float* __restrict__ x, const float* __restrict__ W,
    const float* __restrict__ a1, const float* __restrict__ a2,
    unsigned short* __restrict__ hbT, float* __restrict__ s1, float* __restrict__ s2)
{
    __shared__ __align__(16) float xs[64][65];
    __shared__ __align__(16) float ws[64][132];
    const int t  = threadIdx.x;
    const int tx = t & 15, ty = t >> 4;
    const int rowbase = blockIdx.x * 64;

    float acc[4][8];
#pragma unroll
    for (int i = 0; i < 4; ++i)
#pragma unroll
        for (int j = 0; j < 8; ++j) acc[i][j] = 0.f;

    for (int kt = 0; kt < KF; kt += 64) {
        {   // stage x tile [64][64]
            int row = t >> 2, k0 = (t & 3) * 16;
            const float4* src = (const float4*)(x + (size_t)(rowbase + row) * KF + kt + k0);
            float4 v0 = src[0], v1 = src[1], v2 = src[2], v3 = src[3];
            xs[row][k0+ 0]=v0.x; xs[row][k0+ 1]=v0.y; xs[row][k0+ 2]=v0.z; xs[row][k0+ 3]=v0.w;
            xs[row][k0+ 4]=v1.x; xs[row][k0+ 5]=v1.y; xs[row][k0+ 6]=v1.z; xs[row][k0+ 7]=v1.w;
            xs[row][k0+ 8]=v2.x; xs[row][k0+ 9]=v2.y; xs[row][k0+10]=v2.z; xs[row][k0+11]=v2.w;
            xs[row][k0+12]=v3.x; xs[row][k0+13]=v3.y; xs[row][k0+14]=v3.z; xs[row][k0+15]=v3.w;
        }
        {   // stage W tile [64][128]
            int k = t >> 2, c0 = (t & 3) * 32;
            const float4* src = (const float4*)(W + (size_t)(kt + k) * DF + c0);
#pragma unroll
            for (int j = 0; j < 8; ++j)
                *(float4*)&ws[k][c0 + j * 4] = src[j];
        }
        __syncthreads();
#pragma unroll 4
        for (int k = 0; k < 64; ++k) {
            float xv[4];
#pragma unroll
            for (int ri = 0; ri < 4; ++ri) xv[ri] = xs[ty * 4 + ri][k];
            float4 w0 = *(float4*)&ws[k][tx * 8];
            float4 w1 = *(float4*)&ws[k][tx * 8 + 4];
#pragma unroll
            for (int ri = 0; ri < 4; ++ri) {
                acc[ri][0] += xv[ri] * w0.x; acc[ri][1] += xv[ri] * w0.y;
                acc[ri][2] += xv[ri] * w0.z; acc[ri][3] += xv[ri] * w0.w;
                acc[ri][4] += xv[ri] * w1.x; acc[ri][5] += xv[ri] * w1.y;
                acc[ri][6] += xv[ri] * w1.z; acc[ri][7] += xv[ri] * w1.w;
            }
        }
        __syncthreads();
    }
#pragma unroll
    for (int ci = 0; ci < 8; ++ci) {
        int col = tx * 8 + ci;
        ushort4 u;
        u.x = f2bf(acc[0][ci]); u.y = f2bf(acc[1][ci]);
        u.z = f2bf(acc[2][ci]); u.w = f2bf(acc[3][ci]);
        *(ushort4*)(hbT + (size_t)col * NR + rowbase + ty * 4) = u;
    }
    float4 a1lo = *(const float4*)(a1 + tx * 8), a1hi = *(const float4*)(a1 + tx * 8 + 4);
    float4 a2lo = *(const float4*)(a2 + tx * 8), a2hi = *(const float4*)(a2 + tx * 8 + 4);
#pragma unroll
    for (int ri = 0; ri < 4; ++ri) {
        float p1 = acc[ri][0]*a1lo.x + acc[ri][1]*a1lo.y + acc[ri][2]*a1lo.z + acc[ri][3]*a1lo.w
                 + acc[ri][4]*a1hi.x + acc[ri][5]*a1hi.y + acc[ri][6]*a1hi.z + acc[ri][7]*a1hi.w;
        float p2 = acc[ri][0]*a2lo.x + acc[ri][1]*a2lo.y + acc[ri][2]*a2lo.z + acc[ri][3]*a2lo.w
                 + acc[ri][4]*a2hi.x + acc[ri][5]*a2hi.y + acc[ri][6]*a2hi.z + acc[ri][7]*a2hi.w;
#pragma unroll
        for (int off = 8; off > 0; off >>= 1) {
            p1 += __shfl_xor(p1, off);
            p2 += __shfl_xor(p2, off);
        }
        if (tx == 0) {
            s1[rowbase + ty * 4 + ri] = p1;
            s2[rowbase + ty * 4 + ri] = p2;
        }
    }
}

// ---------- Kernel A2: global max of s1 (one block) --------------------------
__global__ __launch_bounds__(1024) void k_gmax(
    const float* __restrict__ s1, float* __restrict__ gmax)
{
    __shared__ float red[16];
    const int t = threadIdx.x;
    float m = NEGBIG;
    const float4* s4 = (const float4*)s1;
    for (int i = t; i < NR / 4; i += 1024) {
        float4 v = s4[i];
        m = fmaxf(fmaxf(v.x, v.y), fmaxf(fmaxf(v.z, v.w), m));
    }
#pragma unroll
    for (int off = 32; off > 0; off >>= 1) m = fmaxf(m, __shfl_xor(m, off));
    if ((t & 63) == 0) red[t >> 6] = m;
    __syncthreads();
    if (t < 16) {
        m = red[t];
#pragma unroll
        for (int off = 8; off > 0; off >>= 1) m = fmaxf(m, __shfl_xor(m, off));
        if (t == 0) gmax[0] = m;
    }
}

// ---------- Kernel B: flash over adj. 128 Q-rows/block (8 waves x 16 rows),
// global_load_lds ring-3, counted vmcnt. hbT stage SHARED by 8 waves:
// per-iter VMEM = 16KB adj + 8KB hbT (ratio 2:1 vs old 1:1 -> 25% less traffic).
__global__ __launch_bounds__(512, 4) void k_flash(
    const int* __restrict__ adj, const unsigned short* __restrict__ hbT,
    const float* __restrict__ s1, const float* __restrict__ s2,
    const float* __restrict__ gmaxp,
    float* __restrict__ num, float* __restrict__ lC)
{
    // ring stages: adj [128 rows][8 slots of 16B, slot ^ (row&7)],
    //              hbT [128 feats][4 slots of 16B, slot ^ ((feat>>1)&3)]
    __shared__ __align__(16) int            adjring[3][4096];
    __shared__ __align__(16) unsigned short hbtring[3][4096];
    __shared__ __align__(16) float          s1lds[CW];

    const int t    = threadIdx.x;
    const int wid  = t >> 6, lane = t & 63;
    const int r    = lane & 15, g = lane >> 4;
    const int rowb = blockIdx.x * ROWS;
    const int prow = rowb + wid * 16 + r;
    const int chunk = blockIdx.y;
    const int j0 = chunk * CW;

    // one-time: stage s1 chunk (CW floats) into LDS
    if (t < CW / 4) *(float4*)&s1lds[t * 4] = *(const float4*)(s1 + j0 + t * 4);

    const float gm  = gmaxp[0];
    const float s2r = s2[prow];
    const float zub = s2r + gm;
    const float Mi  = fmaxf(zub, 0.2f * zub);   // lrelu(upper bound) >= every row logit

    // ---- adj staging: wave wid stages its own 16 rows via 2 gload16
    const int arow  = wid * 16 + (lane >> 3);
    const int acol4 = ((lane & 7) ^ (lane >> 3)) * 4;
    const int* agp0 = adj + (size_t)(rowb + arow) * NR + j0 + acol4;
    const int* agp1 = agp0 + (size_t)8 * NR;
    const int aldso0 = (wid * 16 + 0) * 128;     // LDS byte offs (wave-uniform)
    const int aldso1 = (wid * 16 + 8) * 128;

    // ---- hbT staging: wave wid stages feats wid*16..+16 via 1 gload16
    const int hrow  = wid * 16 + (lane >> 2);
    const int hcol8 = ((lane & 3) ^ ((lane >> 3) & 3)) * 8;
    const unsigned short* hgp0 = hbT + (size_t)hrow * NR + j0 + hcol8;
    const int hldso0 = wid * 16 * 64;

    // ---- read-side swizzled offsets (lane-constant)
    const int a_off0 = (wid * 16 + r) * 128 + (((2 * g + 0) ^ (r & 7)) * 16);
    const int a_off1 = (wid * 16 + r) * 128 + (((2 * g + 1) ^ (r & 7)) * 16);
    const int h_base = r * 64 + ((g ^ ((r >> 1) & 3)) * 16);    // + f*1024

#define ISSUE(st) do { \
        const int sl_ = (st) % 3; \
        const size_t go_ = (size_t)(((st) % NSTEP) * 32); \
        gload16(agp0 + go_, (char*)&adjring[sl_][0] + aldso0); \
        gload16(agp1 + go_, (char*)&adjring[sl_][0] + aldso1); \
        gload16(hgp0 + go_, (char*)&hbtring[sl_][0] + hldso0); \
    } while (0)

    float lsum = 0.f;
    f32x4 acc[8];
#pragma unroll
    for (int f = 0; f < 8; ++f) acc[f] = f32x4{0.f, 0.f, 0.f, 0.f};

    ISSUE(0);
    ISSUE(1);

    for (int j = 0; j < NSTEP; ++j) {
        // stage j landed when <=3 of this wave's vmem remain (stage j+1 only).
        asm volatile("s_waitcnt vmcnt(3) lgkmcnt(0)" ::: "memory");
        __builtin_amdgcn_s_barrier();
        __builtin_amdgcn_sched_barrier(0);
        ISSUE(j + 2);   // safe: slot (j+2)%3 == (j-1)%3 fully consumed before barrier

        const int sl = j % 3;
        const int4 Aa = *(const int4*)((const char*)&adjring[sl][0] + a_off0);
        const int4 Ab = *(const int4*)((const char*)&adjring[sl][0] + a_off1);
        const float4 Sa = *(const float4*)&s1lds[j * 32 + g * 8];
        const float4 Sb = *(const float4*)&s1lds[j * 32 + g * 8 + 4];

        bf16x8 pf;
#define PROC(mm, ss, idx) { \
            float t0 = (ss) + s2r; \
            float lr = fmaxf(t0, 0.2f * t0); \
            float q  = __expf(lr - Mi); \
            float p  = ((mm) > 0) ? q : 0.f; \
            lsum += p; \
            pf[idx] = (__bf16)p; }
        PROC(Aa.x, Sa.x, 0) PROC(Aa.y, Sa.y, 1)
        PROC(Aa.z, Sa.z, 2) PROC(Aa.w, Sa.w, 3)
        PROC(Ab.x, Sb.x, 4) PROC(Ab.y, Sb.y, 5)
        PROC(Ab.z, Sb.z, 6) PROC(Ab.w, Sb.w, 7)
#undef PROC

        const char* hb = (const char*)&hbtring[sl][0] + h_base;
#pragma unroll
        for (int f = 0; f < 8; ++f) {
            bf16x8 bfr = *(const bf16x8*)(hb + f * 1024);
            acc[f] = __builtin_amdgcn_mfma_f32_16x16x32_bf16(pf, bfr, acc[f], 0, 0, 0);
        }
    }
#undef ISSUE

    lsum += __shfl_xor(lsum, 16);
    lsum += __shfl_xor(lsum, 32);
    if (g == 0) lC[(size_t)chunk * NR + prow] = lsum;

    float* nb = num + (size_t)chunk * NR * DF;
#pragma unroll
    for (int f = 0; f < 8; ++f)
#pragma unroll
        for (int q = 0; q < 4; ++q) {
            int row = rowb + wid * 16 + g * 4 + q;   // C/D layout: row=(lane>>4)*4+reg
            nb[(size_t)row * DF + f * 16 + r] = acc[f][q];
        }
}

// ---------- Kernel C: combine chunk partials (shared M_i -> plain sums) ------
__global__ __launch_bounds__(256) void k_comb(
    const float* __restrict__ num, const float* __restrict__ lC,
    float* __restrict__ out)
{
    const int t   = threadIdx.x;
    const int row = blockIdx.x * 2 + (t >> 7);
    const int f   = t & 127;
    float L = 0.f, o = 0.f;
    for (int c = 0; c < CH; ++c) {
        L += lC[(size_t)c * NR + row];
        o += num[(size_t)c * NR * DF + (size_t)row * DF + f];
    }
    out[(size_t)row * DF + f] = o / L;
}

extern "C" void kernel_launch(void* const* d_in, const int* in_sizes, int n_in,
                              void* d_out, int out_size, void* d_ws, size_t ws_size,
                              hipStream_t stream)
{
    const float* x   = (const float*)d_in[0];
    const int*   adj = (const int*)d_in[1];
    const float* W   = (const float*)d_in[2];
    const float* a1  = (const float*)d_in[3];
    const float* a2  = (const float*)d_in[4];
    float* out = (float*)d_out;

    char* p = (char*)d_ws;
    unsigned short* hbT = (unsigned short*)p; p += (size_t)DF * NR * 2;
    float*          s1  = (float*)p;          p += (size_t)NR * 4;
    float*          s2  = (float*)p;          p += (size_t)NR * 4;
    float*          gmx = (float*)p;          p += 256;
    float*          numb = (float*)p;         p += (size_t)CH * NR * DF * 4;
    float*          lC   = (float*)p;

    k_gemm_h<<<NR / 64, 256, 0, stream>>>(x, W, a1, a2, hbT, s1, s2);
    k_gmax<<<1, 1024, 0, stream>>>(s1, gmx);
    k_flash<<<dim3(NR / ROWS, CH), 512, 0, stream>>>(adj, hbT, s1, s2, gmx, numb, lC);
    k_comb<<<NR / 2, 256, 0, stream>>>(numb, lC, out);
}